// Round 3
// baseline (69.738 us; speedup 1.0000x reference)
//
#include <hip/hip_runtime.h>

// ctx[b,i,d] = tanh(emb[b,i,d] * mean_j emb[b,j,d])
// B=512, I=128, D=64, fp32. Memory-bound: 33.5 MB total traffic, touched once
// -> nontemporal loads/stores, register-resident data, full-occupancy blocks.

#define BB 512
#define II 128
#define DD 64
#define ELEMS_PER_BATCH (II * DD)               // 8192 floats
#define VEC_PER_BATCH   (ELEMS_PER_BATCH / 4)   // 2048 float4
#define BLOCK 1024

// Native clang vector type: __builtin_nontemporal_* requires a real vector,
// not HIP's struct-based float4.
typedef float vf4 __attribute__((ext_vector_type(4)));

__device__ __forceinline__ float fast_tanh(float x) {
    // tanh(x) = 1 - 2/(e^{2x}+1); v_exp_f32 + v_rcp_f32. Correct limits at +-inf.
    float e = __expf(2.0f * x);
    return __fmaf_rn(-2.0f, __builtin_amdgcn_rcpf(e + 1.0f), 1.0f);
}

__global__ __launch_bounds__(BLOCK) void ctx_tanh_kernel(
        const float* __restrict__ emb, float* __restrict__ out) {
    __shared__ vf4 s_part[BLOCK];   // 16 KiB
    __shared__ vf4 s_mean[16];      // 64 mean floats

    const int b = blockIdx.x;
    const int t = threadIdx.x;
    const vf4* __restrict__ gin  = (const vf4*)(emb + (size_t)b * ELEMS_PER_BATCH);
    vf4* __restrict__       gout = (vf4*)(out + (size_t)b * ELEMS_PER_BATCH);

    // Load 2 float4 per thread, keep in registers. j = t + 1024k, and
    // 1024 % 16 == 0 so j % 16 == t % 16 (d-group is k-invariant).
    vf4 v0 = __builtin_nontemporal_load(&gin[t]);
    vf4 v1 = __builtin_nontemporal_load(&gin[t + BLOCK]);

    s_part[t] = v0 + v1;
    __syncthreads();

    // Stage 1: 1024 -> 256 partials (index mod 16 == d-group preserved).
    if (t < 256) {
        s_part[t] = s_part[t] + s_part[t + 256] + s_part[t + 512] + s_part[t + 768];
    }
    __syncthreads();

    // Stage 2: 256 -> 16 means. Partial at index p covers d-group p % 16.
    if (t < 16) {
        vf4 s = (vf4)(0.0f);
        #pragma unroll
        for (int m = 0; m < 16; ++m) s += s_part[t + 16 * m];
        s_mean[t] = s * (1.0f / (float)II);
    }
    __syncthreads();

    const vf4 m = s_mean[t & 15];
    vf4 p0 = v0 * m, p1 = v1 * m;
    vf4 o0, o1;
    o0.x = fast_tanh(p0.x); o0.y = fast_tanh(p0.y);
    o0.z = fast_tanh(p0.z); o0.w = fast_tanh(p0.w);
    o1.x = fast_tanh(p1.x); o1.y = fast_tanh(p1.y);
    o1.z = fast_tanh(p1.z); o1.w = fast_tanh(p1.w);
    __builtin_nontemporal_store(o0, &gout[t]);
    __builtin_nontemporal_store(o1, &gout[t + BLOCK]);
}

extern "C" void kernel_launch(void* const* d_in, const int* in_sizes, int n_in,
                              void* d_out, int out_size, void* d_ws, size_t ws_size,
                              hipStream_t stream) {
    const float* emb = (const float*)d_in[0];
    float* out = (float*)d_out;
    ctx_tanh_kernel<<<dim3(BB), dim3(BLOCK), 0, stream>>>(emb, out);
}

// Round 4
// 68.777 us; speedup vs baseline: 1.0140x; 1.0140x over previous
//
#include <hip/hip_runtime.h>

// ctx[b,i,d] = tanh(emb[b,i,d] * mean_j emb[b,j,d])
// B=512, I=128, D=64, fp32. 33.5 MB single-touch traffic -> memory-bound,
// roofline ~5.3us. Harness re-poison fills (~45us, 256MiB ws) dominate dur_us.

#define BB 512
#define II 128
#define DD 64
#define ELEMS_PER_BATCH (II * DD)               // 8192 floats
#define VEC_PER_BATCH   (ELEMS_PER_BATCH / 4)   // 2048 float4
#define BLOCK 256
#define VPT (VEC_PER_BATCH / BLOCK)             // 8 float4 per thread

typedef float vf4 __attribute__((ext_vector_type(4)));

__device__ __forceinline__ float fast_tanh(float x) {
    // tanh(x) = 1 - 2/(e^{2x}+1); v_exp_f32 + v_rcp_f32. Correct limits at +-inf.
    float e = __expf(2.0f * x);
    return __fmaf_rn(-2.0f, __builtin_amdgcn_rcpf(e + 1.0f), 1.0f);
}

__device__ __forceinline__ vf4 shfl_xor_vf4(vf4 v, int mask) {
    vf4 r;
    r.x = __shfl_xor(v.x, mask, 64);
    r.y = __shfl_xor(v.y, mask, 64);
    r.z = __shfl_xor(v.z, mask, 64);
    r.w = __shfl_xor(v.w, mask, 64);
    return r;
}

__global__ __launch_bounds__(BLOCK) void ctx_tanh_kernel(
        const float* __restrict__ emb, float* __restrict__ out) {
    __shared__ vf4 s_wpart[64];   // 4 waves x 16 d-groups
    __shared__ vf4 s_mean[16];

    const int b = blockIdx.x;
    const int t = threadIdx.x;
    const int lane = t & 63;
    const int wave = t >> 6;
    const vf4* __restrict__ gin  = (const vf4*)(emb + (size_t)b * ELEMS_PER_BATCH);
    vf4* __restrict__       gout = (vf4*)(out + (size_t)b * ELEMS_PER_BATCH);

    // 8 independent nt loads per thread -> high MLP. j = t + 256k, 256%16==0
    // so d-group (j%16) == t%16 is k-invariant.
    vf4 v[VPT];
    #pragma unroll
    for (int k = 0; k < VPT; ++k)
        v[k] = __builtin_nontemporal_load(&gin[t + BLOCK * k]);

    vf4 acc = v[0];
    #pragma unroll
    for (int k = 1; k < VPT; ++k) acc += v[k];

    // Wave-level: lanes l, l^16, l^32 (and combos) share d-group l%16.
    acc += shfl_xor_vf4(acc, 16);
    acc += shfl_xor_vf4(acc, 32);
    if (lane < 16) s_wpart[wave * 16 + lane] = acc;
    __syncthreads();

    // 4 wave-partials per d-group -> mean.
    if (t < 16) {
        vf4 s = s_wpart[t] + s_wpart[t + 16] + s_wpart[t + 32] + s_wpart[t + 48];
        s_mean[t] = s * (1.0f / (float)II);
    }
    __syncthreads();

    const vf4 m = s_mean[t & 15];
    #pragma unroll
    for (int k = 0; k < VPT; ++k) {
        vf4 p = v[k] * m;
        vf4 o;
        o.x = fast_tanh(p.x); o.y = fast_tanh(p.y);
        o.z = fast_tanh(p.z); o.w = fast_tanh(p.w);
        __builtin_nontemporal_store(o, &gout[t + BLOCK * k]);
    }
}

extern "C" void kernel_launch(void* const* d_in, const int* in_sizes, int n_in,
                              void* d_out, int out_size, void* d_ws, size_t ws_size,
                              hipStream_t stream) {
    const float* emb = (const float*)d_in[0];
    float* out = (float*)d_out;
    ctx_tanh_kernel<<<dim3(BB), dim3(BLOCK), 0, stream>>>(emb, out);
}